// Round 13
// baseline (496.659 us; speedup 1.0000x reference)
//
#include <hip/hip_runtime.h>
#include <hip/hip_bf16.h>

typedef __hip_bfloat16 bf16;
typedef unsigned long long ull;

#define BB 4
#define NN 2048
#define CCH 128
#define DDM 128
#define KNB 16
#define HHD 64
#define AAD 512
#define PP (BB*NN)

typedef __attribute__((ext_vector_type(8))) short short8;
typedef __attribute__((ext_vector_type(16))) float f32x16;

__device__ __forceinline__ float b2f(bf16 x) { return __bfloat162float(x); }
__device__ __forceinline__ bf16 f2b(float x) { return __float2bfloat16(x); }

__device__ __forceinline__ float ldany(const void* p, size_t i, int f32) {
  return f32 ? ((const float*)p)[i] : __bfloat162float(((const bf16*)p)[i]);
}

__device__ __forceinline__ long pack4(float a, float b, float c, float d) {
  union { bf16 h[4]; long l; } u;
  u.h[0] = f2b(a); u.h[1] = f2b(b); u.h[2] = f2b(c); u.h[3] = f2b(d);
  return u.l;
}
__device__ __forceinline__ void unpack4(long l, float* o) {
  union { bf16 h[4]; long l; } u; u.l = l;
  o[0] = b2f(u.h[0]); o[1] = b2f(u.h[1]); o[2] = b2f(u.h[2]); o[3] = b2f(u.h[3]);
}

__device__ __forceinline__ short8 ldfrag(const bf16* base, int row, int stride, int k0, int hl) {
  const bf16* p = base + (size_t)row * stride + k0 + (hl << 3);
  union { short8 v; long l[2]; } u;
  u.l[0] = *(const long*)p;
  u.l[1] = *(const long*)(p + 4);
  return u.v;
}

__device__ __forceinline__ f32x16 MFMA(short8 a, short8 b, f32x16 c) {
  return __builtin_amdgcn_mfma_f32_32x32x16_bf16(a, b, c, 0, 0, 0);
}

struct PtrArr { const void* p[36]; int n[36]; };
struct CvtTab { int src[16]; int off[16]; int n[16]; int isb[16]; };
struct G4 { const bf16* X[4]; int K[4]; int woff[4]; int boff[4]; bf16* out[4]; int relu[4]; };

// ---------- dtype sniffer ----------
__global__ __launch_bounds__(256) void sniff_kern(PtrArr pa, int* __restrict__ flags) {
  int t = blockIdx.x;
  const bf16* x = (const bf16*)pa.p[t];
  int n = pa.n[t]; if (n > 4096) n = 4096;
  __shared__ int cnt;
  if (threadIdx.x == 0) cnt = 0;
  __syncthreads();
  int c = 0;
  for (int i = threadIdx.x; i < n; i += 256) {
    float v = fabsf(__bfloat162float(x[i]));
    if (v == 0.f || (v >= 1e-6f && v <= 1024.f)) c++;
  }
  atomicAdd(&cnt, c);
  __syncthreads();
  if (threadIdx.x == 0) flags[t] = (cnt >= (n * 7) / 8) ? 0 : 1;
}

// ---------- fused convert: y<2 -> attn weight images (set=y); y>=2 -> GEMM arena entry ----------
__global__ __launch_bounds__(256) void cvtprep_kern(PtrArr pa, CvtTab tab,
                                                    const int* __restrict__ flags,
                                                    bf16* __restrict__ warena, float* __restrict__ barena,
                                                    bf16* __restrict__ w1img0, bf16* __restrict__ w2img0,
                                                    bf16* __restrict__ cw2img0, float* __restrict__ fb0,
                                                    bf16* __restrict__ w1img1, bf16* __restrict__ w2img1,
                                                    bf16* __restrict__ cw2img1, float* __restrict__ fb1) {
  int y = blockIdx.y;
  if (y >= 2) {
    int e = y - 2;
    int i = blockIdx.x * 256 + threadIdx.x;
    if (i >= tab.n[e]) return;
    float v = ldany(pa.p[tab.src[e]], i, flags[tab.src[e]]);
    if (tab.isb[e]) barena[tab.off[e] + i] = v;
    else warena[tab.off[e] + i] = f2b(v);
    return;
  }
  int set = y;
  int cIdx = set ? 20 : 16, aIdx = set ? 28 : 24, dd = set ? 2 : 3;
  bf16* w1img = set ? w1img1 : w1img0;
  bf16* w2img = set ? w2img1 : w2img0;
  bf16* cw2img = set ? cw2img1 : cw2img0;
  float* fb = set ? fb1 : fb0;
  const void* cw1 = pa.p[cIdx];     const void* cb1 = pa.p[cIdx + 1];
  const void* cw2 = pa.p[cIdx + 2]; const void* cb2 = pa.p[cIdx + 3];
  const void* aw1 = pa.p[aIdx];     const void* ab1 = pa.p[aIdx + 1];
  const void* aw2 = pa.p[aIdx + 2]; const void* ab2 = pa.p[aIdx + 3];
  int i = blockIdx.x * 256 + threadIdx.x;
  const int fcw1 = flags[cIdx], fcb1 = flags[cIdx + 1];
  const int fcw2 = flags[cIdx + 2], fcb2 = flags[cIdx + 3];
  const int faw1 = flags[aIdx], fab1 = flags[aIdx + 1];
  const int faw2 = flags[aIdx + 2], fab2 = flags[aIdx + 3];
  float* ab1f = fb;          // 512
  float* ab2f = fb + 512;    // 128
  float* cb1f = fb + 640;    // 64
  float* cb2f = fb + 704;    // 128
  float* cw1f = fb + 832;    // 192
  if (i < 65536) {                       // w1img: [h_glob 512][132]
    int hg = i >> 7, c = i & 127;
    w1img[(size_t)hg * 132 + c] = f2b(ldany(aw1, i, faw1));
  } else if (i < 131072) {               // w2img: [ac*128+o][132] col=h_local
    int j = i - 65536;
    int o = j >> 9, hh = j & 511;
    int ac = hh >> 7, hloc = hh & 127;
    w2img[(size_t)(ac * 128 + o) * 132 + hloc] = f2b(ldany(aw2, j, faw2));
  } else if (i < 139264) {               // cw2img: [o 128][68]
    int j = i - 131072;
    int o = j >> 6, h = j & 63;
    cw2img[o * 68 + h] = f2b(ldany(cw2, j, fcw2));
  } else if (i < 139776) {
    int j = i - 139264; ab1f[j] = ldany(ab1, j, fab1);
  } else if (i < 139904) {
    int j = i - 139776; ab2f[j] = ldany(ab2, j, fab2);
  } else if (i < 139968) {
    int j = i - 139904; cb1f[j] = ldany(cb1, j, fcb1);
  } else if (i < 140096) {
    int j = i - 139968; cb2f[j] = ldany(cb2, j, fcb2);
  } else if (i < 140288) {
    int j = i - 140096;
    int h = j / 3, c = j % 3;
    cw1f[j] = (c < dd) ? ldany(cw1, h * dd + c, fcw1) : 0.f;
  }
}

// ---------- fused transpose + W' prep ----------
// bx<512: key/query -> catT; bx<768: coords; bx>=768: W' = wv@wkq (+ bias2' = wv·bkq)
__global__ __launch_bounds__(256) void trall_kern(const void* __restrict__ keyp,
                                                  const void* __restrict__ qryp,
                                                  const void* __restrict__ xyzp,
                                                  const void* __restrict__ posp,
                                                  const int* __restrict__ flags,
                                                  bf16* __restrict__ catT,
                                                  float* __restrict__ xyzT,
                                                  float* __restrict__ posT,
                                                  bf16* __restrict__ warena,
                                                  float* __restrict__ barena) {
  int bx = blockIdx.x;
  int tid = threadIdx.x;
  if (bx < 512) {
    __shared__ float tile[64][65];
    int xx = bx & 31, yy = (bx >> 5) & 1, zz = bx >> 6;
    int b = zz & 3, half = zz >> 2;
    const void* src = half ? qryp : keyp;
    const int f32 = flags[2 + half];
    int n0 = xx * 64, c0 = yy * 64;
    int tx = tid & 63, ty = tid >> 6;
    for (int r = ty; r < 64; r += 4)
      tile[r][tx] = ldany(src, (size_t)(b * 128 + c0 + r) * NN + n0 + tx, f32);
    __syncthreads();
    for (int r = ty; r < 64; r += 4)
      catT[(size_t)(b * NN + n0 + r) * 256 + half * 128 + c0 + tx] = __float2bfloat16(tile[tx][r]);
    return;
  }
  if (bx < 768) {
    int cb = bx - 512;                 // 0..255
    int which = cb >> 7;               // 0: xyz, 1: pos
    const void* src = which ? posp : xyzp;
    float* dst = which ? posT : xyzT;
    int dd = which ? 2 : 3;
    const int f32 = flags[which];
    int i = (cb & 127) * 256 * 2 + tid;
    for (int rep = 0; rep < 2; ++rep, i += 256) {
      if (i < PP * 4) {
        int p = i >> 2, j = i & 3;
        int b = p >> 11, n = p & (NN - 1);
        dst[i] = (j < dd) ? ldany(src, (size_t)(b * dd + j) * NN + n, f32) : 0.f;
      }
    }
    return;
  }
  int bx2 = bx - 768;
  const bf16* wv = warena + 114688;
  const bf16* wkq = warena + 131072;
  if (bx2 < 64) {                       // W'[i][j] = sum_k wv[i][k]*wkq[k][j]
    int i = bx2 * 256 + tid;
    int row = i >> 7, col = i & 127;
    float acc = 0.f;
    for (int k = 0; k < 128; ++k)
      acc += b2f(wv[row * 128 + k]) * b2f(wkq[k * 128 + col]);
    warena[163840 + i] = f2b(acc);
  } else if (tid < 128) {               // bias2'[i] = sum_k wv[i][k]*bkq[k]
    float acc = 0.f;
    const float* bkq = barena + 768;
    for (int k = 0; k < 128; ++k)
      acc += b2f(wv[tid * 128 + k]) * bkq[k];
    barena[1024 + tid] = acc;
  }
}

// ---------- MEGA: bx<2048 -> kNN (both sets); bx>=2048 -> frontend gemm4 (512 thr) ----------
__global__ __launch_bounds__(512) void mega_kern(
    const float* __restrict__ xyzT, const float* __restrict__ posT,
    int* __restrict__ idx1, int* __restrict__ idx2,
    G4 g, const bf16* __restrict__ warena, const float* __restrict__ barena) {
  __shared__ __attribute__((aligned(16))) char smem[33280];
  int bx = blockIdx.x;
  int tid = threadIdx.x, lane = tid & 63, wvv = tid >> 6;
  if (bx < 2048) {
    // ---- kNN path: 8 points/block; lowest-16-of-32 network + wave merge ----
    float4* cds = (float4*)smem;
    int set = bx >> 10;
    int pblk = bx & 1023;
    const float* coordsT = set ? posT : xyzT;
    int* idxout = set ? idx2 : idx1;
    int p0 = pblk * 8, b = p0 >> 11;
    for (int j = tid; j < NN; j += 512)
      cds[j] = *(const float4*)&coordsT[((size_t)(b << 11) + j) * 4];
    __syncthreads();
    int p = p0 + wvv, n = p & (NN - 1);
    float4 cc = cds[n];
    float sqi = __fadd_rn(__fadd_rn(__fmul_rn(cc.x, cc.x), __fmul_rn(cc.y, cc.y)),
                          __fmul_rn(cc.z, cc.z));
    ull t[32];
#pragma unroll
    for (int s = 0; s < 32; ++s) {
      int j = (s << 6) | lane;
      float4 q = cds[j];
      float sqj = __fadd_rn(__fadd_rn(__fmul_rn(q.x, q.x), __fmul_rn(q.y, q.y)),
                            __fmul_rn(q.z, q.z));
      float dt  = __fadd_rn(__fadd_rn(__fmul_rn(cc.x, q.x), __fmul_rn(cc.y, q.y)),
                            __fmul_rn(cc.z, q.z));
      float d2 = __fsub_rn(__fadd_rn(sqi, sqj), __fmul_rn(2.f, dt));
      unsigned u = __float_as_uint(d2);
      u = (u & 0x80000000u) ? ~u : (u | 0x80000000u);   // sortable ascending
      t[s] = ((ull)u << 32) | (unsigned)j;
    }
    // sort each 16-half ascending (bitonic), keep lowest 16 of 32, re-sort
#pragma unroll
    for (int base = 0; base < 32; base += 16) {
#pragma unroll
      for (int k = 2; k <= 16; k <<= 1) {
#pragma unroll
        for (int j = k >> 1; j > 0; j >>= 1) {
#pragma unroll
          for (int i = 0; i < 16; ++i) {
            int l = i ^ j;
            if (l > i) {
              bool up = ((i & k) == 0);
              ull a = t[base + i], c = t[base + l];
              ull lo = a < c ? a : c;
              ull hi = a < c ? c : a;
              t[base + i] = up ? lo : hi;
              t[base + l] = up ? hi : lo;
            }
          }
        }
      }
    }
#pragma unroll
    for (int i = 0; i < 16; ++i) {      // lower half of bitonic merge-32
      ull a = t[i], c = t[31 - i];
      t[i] = a < c ? a : c;
    }
#pragma unroll
    for (int j = 8; j > 0; j >>= 1) {   // bitonic sequence -> sorted ascending
#pragma unroll
      for (int i = 0; i < 16; ++i) {
        int l = i ^ j;
        if (l > i) {
          ull a = t[i], c = t[l];
          ull lo = a < c ? a : c;
          ull hi = a < c ? c : a;
          t[i] = lo; t[l] = hi;
        }
      }
    }
    for (int r = 0; r < KNB; ++r) {
      ull h = t[0];
      ull m = h;
#pragma unroll
      for (int off = 1; off < 64; off <<= 1) {
        ull o = __shfl_xor(m, off);
        m = o < m ? o : m;
      }
      if (lane == 0) idxout[(size_t)p * KNB + r] = (int)(m & 0xffffffffu);
      if (h == m) {
#pragma unroll
        for (int i = 0; i < 15; ++i) t[i] = t[i + 1];
        t[15] = ~0ull;
      }
    }
    return;
  }
  // ---- gemm4 path ----
  {
    bf16* XT = (bf16*)smem;
    int bx2 = bx - 2048;
    int op = bx2 >> 7, ptile = bx2 & 127;
    const bf16* X = g.X[op];
    int K = g.K[op];
    const bf16* Wb = warena + g.woff[op];
    const float* bias = barena + g.boff[op];
    bf16* out = g.out[op];
    int relu = g.relu[op];
    int hl = lane >> 5, cA = lane & 31;
    int p0 = ptile * 64;
    int SK = K + 4;
    int kc = K >> 3;
    for (int c = tid; c < 64 * kc; c += 512) {
      int r = c / kc, col = (c % kc) << 3;
      *(float4*)&XT[r * SK + col] = *(const float4*)&X[(size_t)(p0 + r) * 256 + col];
    }
    __syncthreads();
    int o0 = (wvv & 3) * 32;
    int tt = wvv >> 2;
    f32x16 acc;
#pragma unroll
    for (int r = 0; r < 16; ++r) {
      int o = o0 + (r & 3) + 8 * (r >> 2) + 4 * hl;
      acc[r] = bias[o];
    }
    for (int ks = 0; ks < (K >> 4); ++ks) {
      short8 af = ldfrag(Wb, o0 + cA, K, ks * 16, hl);
      short8 b0 = ldfrag(XT, tt * 32 + cA, SK, ks * 16, hl);
      acc = MFMA(af, b0, acc);
    }
    int m = p0 + tt * 32 + cA;
#pragma unroll
    for (int q = 0; q < 4; ++q) {
      int ob = o0 + 8 * q + 4 * hl;
      float v[4] = {acc[4*q+0], acc[4*q+1], acc[4*q+2], acc[4*q+3]};
      if (relu) {
        v[0] = fmaxf(v[0], 0.f); v[1] = fmaxf(v[1], 0.f);
        v[2] = fmaxf(v[2], 0.f); v[3] = fmaxf(v[3], 0.f);
      }
      *(long*)(out + (size_t)m * 128 + ob) = pack4(v[0], v[1], v[2], v[3]);
    }
  }
}

// ---------- chained MFMA GEMM: Y1 = X·W1^T + b1 (+add1) [-> out1?]; out2 = Y1·W2^T + b2 ----------
__global__ __launch_bounds__(256) void gemm_chain_kern(
    const bf16* __restrict__ X, const bf16* __restrict__ warena,
    const float* __restrict__ barena,
    int w1off, int b1off, const bf16* __restrict__ add1, bf16* __restrict__ out1,
    int w2off, int b2off, bf16* __restrict__ out2) {
  __shared__ __attribute__((aligned(16))) bf16 XT[32 * 132];
  __shared__ __attribute__((aligned(16))) bf16 YT[32 * 132];
  int tid = threadIdx.x, lane = tid & 63, wv = tid >> 6;
  int hl = lane >> 5, cA = lane & 31;
  int p0 = blockIdx.x * 32;
  for (int c = tid; c < 32 * 16; c += 256) {
    int r = c >> 4, col = (c & 15) << 3;
    *(float4*)&XT[r * 132 + col] = *(const float4*)&X[(size_t)(p0 + r) * 128 + col];
  }
  __syncthreads();
  int o0 = wv * 32;
  const bf16* W1 = warena + w1off;
  const float* b1 = barena + b1off;
  f32x16 acc;
#pragma unroll
  for (int r = 0; r < 16; ++r) {
    int o = o0 + (r & 3) + 8 * (r >> 2) + 4 * hl;
    acc[r] = b1[o];
  }
#pragma unroll
  for (int ks = 0; ks < 8; ++ks) {
    short8 af = ldfrag(W1, o0 + cA, 128, ks * 16, hl);
    short8 b0 = ldfrag(XT, cA, 132, ks * 16, hl);
    acc = MFMA(af, b0, acc);
  }
  int m = p0 + cA;
#pragma unroll
  for (int q = 0; q < 4; ++q) {
    int ob = o0 + 8 * q + 4 * hl;
    float v[4] = {acc[4*q+0], acc[4*q+1], acc[4*q+2], acc[4*q+3]};
    if (add1) {
      float av[4];
      unpack4(*(const long*)(add1 + (size_t)m * 128 + ob), av);
      v[0] += av[0]; v[1] += av[1]; v[2] += av[2]; v[3] += av[3];
    }
    long pk = pack4(v[0], v[1], v[2], v[3]);
    *(long*)&YT[cA * 132 + ob] = pk;
    if (out1) *(long*)(out1 + (size_t)m * 128 + ob) = pk;
  }
  __syncthreads();
  const bf16* W2 = warena + w2off;
  const float* b2 = barena + b2off;
  f32x16 acc2;
#pragma unroll
  for (int r = 0; r < 16; ++r) {
    int o = o0 + (r & 3) + 8 * (r >> 2) + 4 * hl;
    acc2[r] = b2[o];
  }
#pragma unroll
  for (int ks = 0; ks < 8; ++ks) {
    short8 af = ldfrag(W2, o0 + cA, 128, ks * 16, hl);
    short8 b0 = ldfrag(YT, cA, 132, ks * 16, hl);
    acc2 = MFMA(af, b0, acc2);
  }
#pragma unroll
  for (int q = 0; q < 4; ++q) {
    int ob = o0 + 8 * q + 4 * hl;
    *(long*)(out2 + (size_t)m * 128 + ob) =
        pack4(acc2[4*q+0], acc2[4*q+1], acc2[4*q+2], acc2[4*q+3]);
  }
}

// ---------- MFMA fused kNN attention + fused output GEMM ----------
// outMode 0: out = wout·agg + bout + VF (value2) -> token-major bf16 (outAny)
// outMode 1: out = wout·agg + bout + residG    -> (B,128,N) layout (dtype flags[2])
#define SMEM_BYTES 72192
__global__ __launch_bounds__(512, 4) void attn_mfma(
    const bf16* __restrict__ centerT, const bf16* __restrict__ gatherT,
    const float* __restrict__ coordsT, const bf16* __restrict__ vfeatT,
    const int* __restrict__ idx,
    const bf16* __restrict__ w1img, const bf16* __restrict__ w2img,
    const bf16* __restrict__ cw2img, const float* __restrict__ fb,
    const bf16* __restrict__ wout, const float* __restrict__ bout,
    const bf16* __restrict__ residG, void* __restrict__ outAny, int outMode,
    const int* __restrict__ flags) {
  extern __shared__ char smem[];
  bf16* XS  = (bf16*)(smem);            // [128][132]
  bf16* HT  = (bf16*)(smem + 33792);    // [128][132]
  bf16* HC  = HT;                       // [128][68] aliases HT
  bf16* CFE = (bf16*)(smem + 67584);    // [8][128]
  bf16* VF  = (bf16*)(smem + 69632);    // [8][128]
  int*  NID = (int*)(smem + 71680);     // [128]
  const float* ab1f = fb;
  const float* ab2f = fb + 512;
  const float* cb1f = fb + 640;
  const float* cb2f = fb + 704;
  const float* cw1f = fb + 832;

  int tid = threadIdx.x, lane = tid & 63, wv = tid >> 6;
  int hl = lane >> 5, cA = lane & 31;
  int P0 = blockIdx.x * 8, b = P0 >> 11;

  if (tid < 128) NID[tid] = (b << 11) + idx[(size_t)(P0 + (tid >> 4)) * KNB + (tid & 15)];
  for (int i = tid; i < 1024; i += 512) {
    int g = i >> 7, d = i & 127;
    CFE[i] = centerT[(size_t)(P0 + g) * 128 + d];
    VF[i]  = vfeatT[(size_t)(P0 + g) * 128 + d];
  }
  __syncthreads();

  // phase 1: coord hidden HC + XS base (= cfe - gathered)
  {
    int m = tid >> 2, sub = tid & 3;
    float4 ccd = *(const float4*)&coordsT[(size_t)(P0 + (m >> 4)) * 4];
    float4 nbd = *(const float4*)&coordsT[(size_t)NID[m] * 4];
    float r0 = ccd.x - nbd.x, r1 = ccd.y - nbd.y, r2 = ccd.z - nbd.z;
    int h0 = sub * 16;
    for (int hh = h0; hh < h0 + 16; hh += 4) {
      float a0 = fmaxf(cb1f[hh+0] + cw1f[(hh+0)*3]*r0 + cw1f[(hh+0)*3+1]*r1 + cw1f[(hh+0)*3+2]*r2, 0.f);
      float a1 = fmaxf(cb1f[hh+1] + cw1f[(hh+1)*3]*r0 + cw1f[(hh+1)*3+1]*r1 + cw1f[(hh+1)*3+2]*r2, 0.f);
      float a2 = fmaxf(cb1f[hh+2] + cw1f[(hh+2)*3]*r0 + cw1f[(hh+2)*3+1]*r1 + cw1f[(hh+2)*3+2]*r2, 0.f);
      float a3 = fmaxf(cb1f[hh+3] + cw1f[(hh+3)*3]*r0 + cw1f[(hh+3)*3+1]*r1 + cw1f[(hh+3)*3+2]*r2, 0.f);
      *(long*)&HC[m * 68 + hh] = pack4(a0, a1, a2, a3);
    }
    const bf16* grow = gatherT + (size_t)NID[m] * 128 + sub * 32;
    const bf16* crow = CFE + ((m >> 4) << 7) + sub * 32;
    for (int j = 0; j < 32; j += 4) {
      float gv[4], cv[4];
      unpack4(*(const long*)(grow + j), gv);
      unpack4(*(const long*)(crow + j), cv);
      *(long*)&XS[m * 132 + sub * 32 + j] =
          pack4(cv[0] - gv[0], cv[1] - gv[1], cv[2] - gv[2], cv[3] - gv[3]);
    }
  }
  __syncthreads();

  int r0s = (wv & 3) * 32;     // output-row strip (o / h)
  int mt0 = (wv >> 2) * 64;    // token strip (2 tiles of 32)

  // preload chunk-0 W1 fragments (in flight across the emb GEMM)
  short8 pf[8];
#pragma unroll
  for (int ks = 0; ks < 8; ++ks)
    pf[ks] = ldfrag(w1img, r0s + cA, 132, ks * 16, hl);

  // phase 2: emb GEMM (C_e[o][m] = cw2 @ HC + cb2), RMW into XS
  {
    f32x16 eacc[2];
#pragma unroll
    for (int r = 0; r < 16; ++r) {
      int o = r0s + (r & 3) + 8 * (r >> 2) + 4 * hl;
      float bv = cb2f[o];
      eacc[0][r] = bv; eacc[1][r] = bv;
    }
    for (int k0 = 0; k0 < 64; k0 += 16) {
      short8 af = ldfrag(cw2img, r0s + cA, 68, k0, hl);
      short8 b0 = ldfrag(HC, mt0 + cA, 68, k0, hl);
      short8 b1 = ldfrag(HC, mt0 + 32 + cA, 68, k0, hl);
      eacc[0] = MFMA(af, b0, eacc[0]);
      eacc[1] = MFMA(af, b1, eacc[1]);
    }
#pragma unroll
    for (int t = 0; t < 2; ++t) {
      int m = mt0 + t * 32 + cA;
#pragma unroll
      for (int q = 0; q < 4; ++q) {
        int ob = r0s + 8 * q + 4 * hl;
        bf16* px = &XS[m * 132 + ob];
        float xv[4];
        unpack4(*(long*)px, xv);
        *(long*)px = pack4(xv[0] + eacc[t][4*q+0], xv[1] + eacc[t][4*q+1],
                           xv[2] + eacc[t][4*q+2], xv[3] + eacc[t][4*q+3]);
      }
    }
  }
  __syncthreads();

  // preload XS B-fragments (reused by GEMM1 of all 4 chunks)
  short8 xsf[2][8];
#pragma unroll
  for (int ks = 0; ks < 8; ++ks) {
    xsf[0][ks] = ldfrag(XS, mt0 + cA, 132, ks * 16, hl);
    xsf[1][ks] = ldfrag(XS, mt0 + 32 + cA, 132, ks * 16, hl);
  }

  // logits accumulator (bias-init)
  f32x16 acc2[2];
#pragma unroll
  for (int r = 0; r < 16; ++r) {
    int o = r0s + (r & 3) + 8 * (r >> 2) + 4 * hl;
    float bv = ab2f[o];
    acc2[0][r] = bv; acc2[1][r] = bv;
  }

  // chunk loop: 4 x 128 hidden; pf[] rotates W1(chunk ac) -> W2(ac) -> W1(ac+1)
  for (int ac = 0; ac < 4; ++ac) {
    const bf16* w2c = w2img + (size_t)ac * 16896;
    const bf16* w1n = w1img + (size_t)((ac + 1) & 3) * 16896;
    f32x16 acc1[2];
#pragma unroll
    for (int r = 0; r < 16; ++r) {
      int h = r0s + (r & 3) + 8 * (r >> 2) + 4 * hl;
      float bv = ab1f[ac * 128 + h];
      acc1[0][r] = bv; acc1[1][r] = bv;
    }
#pragma unroll
    for (int ks = 0; ks < 8; ++ks) {
      short8 af = pf[ks];
      pf[ks] = ldfrag(w2c, r0s + cA, 132, ks * 16, hl);
      acc1[0] = MFMA(af, xsf[0][ks], acc1[0]);
      acc1[1] = MFMA(af, xsf[1][ks], acc1[1]);
    }
    __syncthreads();
#pragma unroll
    for (int t = 0; t < 2; ++t) {
      int m = mt0 + t * 32 + cA;
#pragma unroll
      for (int q = 0; q < 4; ++q) {
        int hb = r0s + 8 * q + 4 * hl;
        *(long*)&HT[m * 132 + hb] =
            pack4(fmaxf(acc1[t][4*q+0], 0.f), fmaxf(acc1[t][4*q+1], 0.f),
                  fmaxf(acc1[t][4*q+2], 0.f), fmaxf(acc1[t][4*q+3], 0.f));
      }
    }
    __syncthreads();
#pragma unroll
    for (int ks = 0; ks < 8; ++ks) {
      short8 af = pf[ks];
      short8 b0 = ldfrag(HT, mt0 + cA, 132, ks * 16, hl);
      short8 b1 = ldfrag(HT, mt0 + 32 + cA, 132, ks * 16, hl);
      pf[ks] = ldfrag(w1n, r0s + cA, 132, ks * 16, hl);
      acc2[0] = MFMA(af, b0, acc2[0]);
      acc2[1] = MFMA(af, b1, acc2[1]);
    }
  }

  // stash logits into HT (bf16, [m][o] layout) -- HT dead after last GEMM2
  __syncthreads();
#pragma unroll
  for (int t = 0; t < 2; ++t) {
    int m = mt0 + t * 32 + cA;
#pragma unroll
    for (int q = 0; q < 4; ++q) {
      int ob = r0s + 8 * q + 4 * hl;
      *(long*)&HT[m * 132 + ob] = pack4(acc2[t][4*q+0], acc2[t][4*q+1],
                                        acc2[t][4*q+2], acc2[t][4*q+3]);
    }
  }
  __syncthreads();

  // shuffle-free softmax-one + aggregation: wave wv owns point g=wv; lane owns o, o+64
  float agg0, agg1v;
  {
    int g = wv;
    int base = g * 16;
    float vbase0 = b2f(VF[g * 128 + lane])      - b2f(CFE[g * 128 + lane]);
    float vbase1 = b2f(VF[g * 128 + lane + 64]) - b2f(CFE[g * 128 + lane + 64]);
#pragma unroll
    for (int half = 0; half < 2; ++half) {
      int o = lane + half * 64;
      float vb = half ? vbase1 : vbase0;
      float e[16];
      float mx = -3.4e38f;
#pragma unroll
      for (int kk = 0; kk < 16; ++kk) {
        float x = b2f(HT[(base + kk) * 132 + o]);
        e[kk] = x;
        mx = fmaxf(mx, x);
      }
      float s = 0.f;
#pragma unroll
      for (int kk = 0; kk < 16; ++kk) { e[kk] = __expf(e[kk] - mx); s += e[kk]; }
      float inv = 1.f / (1.f + s);
      float acc = 0.f;
#pragma unroll
      for (int kk = 0; kk < 16; ++kk) {
        float xv = b2f(XS[(base + kk) * 132 + o]);
        float gv = b2f(gatherT[(size_t)NID[base + kk] * 128 + o]);
        acc += (e[kk] * inv) * (vb + xv + gv);
      }
      if (half) agg1v = acc; else agg0 = acc;
    }
  }
  __syncthreads();   // all logit/XS reads done; reuse HT rows 0..7 for agg
  {
    int g = wv;
    HT[g * 132 + lane] = f2b(agg0);
    HT[g * 132 + lane + 64] = f2b(agg1v);
  }
  __syncthreads();

  // fused output GEMM: out[m][c] = wout[c]·agg[m] + bout[c] + resid[m][c]
  if (wv < 4) {
    int o0m = wv * 32;
    f32x16 acc;
#pragma unroll
    for (int r = 0; r < 16; ++r) {
      int o = o0m + (r & 3) + 8 * (r >> 2) + 4 * hl;
      acc[r] = bout[o];
    }
#pragma unroll
    for (int ks = 0; ks < 8; ++ks) {
      short8 af = ldfrag(wout, o0m + cA, 128, ks * 16, hl);
      short8 b0 = ldfrag(HT, cA, 132, ks * 16, hl);
      acc = MFMA(af, b0, acc);
    }
    int m = cA;
    if (m < 8) {
      int f32o = outMode ? flags[2] : 0;
      int gp = P0 + m;
      int gb = gp >> 11, gn = gp & (NN - 1);
#pragma unroll
      for (int q = 0; q < 4; ++q) {
        int ob = o0m + 8 * q + 4 * hl;
        float rv[4];
        if (outMode) unpack4(*(const long*)(residG + (size_t)gp * 128 + ob), rv);
        else         unpack4(*(long*)&VF[m * 128 + ob], rv);
        float v0o = acc[4*q+0] + rv[0];
        float v1o = acc[4*q+1] + rv[1];
        float v2o = acc[4*q+2] + rv[2];
        float v3o = acc[4*q+3] + rv[3];
        if (outMode) {
          float vv[4] = {v0o, v1o, v2o, v3o};
#pragma unroll
          for (int i = 0; i < 4; ++i) {
            size_t oi = (size_t)(gb * 128 + ob + i) * NN + gn;
            if (f32o) ((float*)outAny)[oi] = vv[i];
            else ((bf16*)outAny)[oi] = f2b(vv[i]);
          }
        } else {
          *(long*)((bf16*)outAny + (size_t)gp * 128 + ob) = pack4(v0o, v1o, v2o, v3o);
        }
      }
    }
  }
}

extern "C" void kernel_launch(void* const* d_in, const int* in_sizes, int n_in,
                              void* d_out, int out_size, void* d_ws, size_t ws_size,
                              hipStream_t stream) {
  // workspace layout
  int* flags = (int*)d_ws;
  bf16* catT = (bf16*)((float*)d_ws + 64);        // P x 256
  bf16* v0   = catT + (size_t)PP * 256;
  bf16* kT   = v0 + (size_t)PP * 128;
  bf16* qT   = kT + (size_t)PP * 128;
  bf16* sE   = qT + (size_t)PP * 128;             // vT, then value2 (in-place per-row)
  bf16* sF   = sE + (size_t)PP * 128;             // tmp
  bf16* sG   = sF + (size_t)PP * 128;             // shortb
  float* xyzT = (float*)(sG + (size_t)PP * 128);  // P x 4
  float* posT = xyzT + (size_t)PP * 4;
  int* idx1 = (int*)(posT + (size_t)PP * 4);      // P x 16
  int* idx2 = idx1 + (size_t)PP * KNB;            // P x 16
  bf16* w1i1 = (bf16*)(idx2 + (size_t)PP * KNB);  // 4*128*132
  bf16* w2i1 = w1i1 + 67584;
  bf16* cw2i1 = w2i1 + 67584;                     // 128*68
  bf16* w1i2 = cw2i1 + 8704;
  bf16* w2i2 = w1i2 + 67584;
  bf16* cw2i2 = w2i2 + 67584;
  float* fb1 = (float*)(cw2i2 + 8704);            // 1024 floats
  float* fb2 = fb1 + 1024;
  bf16* warena = (bf16*)(fb2 + 1024);             // 163840 + 16384 (W') bf16
  float* barena = (float*)(warena + 180224);      // 1024 + 128 fp32

  PtrArr pa;
  for (int i = 0; i < 36; ++i) { pa.p[i] = d_in[i]; pa.n[i] = in_sizes[i]; }
  sniff_kern<<<dim3(36), 256, 0, stream>>>(pa, flags);

  CvtTab tab;
  int wsrc[8] = {4, 8, 6, 10, 12, 14, 32, 34};
  int woff[8] = {0, 32768, 65536, 81920, 98304, 114688, 131072, 147456};
  int wn[8]   = {32768, 32768, 16384, 16384, 16384, 16384, 16384, 16384};
  int bsrc[8] = {5, 9, 7, 11, 13, 15, 33, 35};
  for (int e = 0; e < 8; ++e) {
    tab.src[e] = wsrc[e]; tab.off[e] = woff[e]; tab.n[e] = wn[e]; tab.isb[e] = 0;
    tab.src[8 + e] = bsrc[e]; tab.off[8 + e] = e * 128; tab.n[8 + e] = 128; tab.isb[8 + e] = 1;
  }
  cvtprep_kern<<<dim3(548, 18), 256, 0, stream>>>(pa, tab, flags, warena, barena,
                                                  w1i1, w2i1, cw2i1, fb1,
                                                  w1i2, w2i2, cw2i2, fb2);

  trall_kern<<<dim3(833), 256, 0, stream>>>(d_in[2], d_in[3], d_in[0], d_in[1],
                                            flags, catT, xyzT, posT, warena, barena);

  // MEGA: kNN (both sets) co-dispatched with the 4-op frontend GEMM
  G4 g4;
  g4.X[0] = catT;       g4.K[0] = 256; g4.woff[0] = 0;      g4.boff[0] = 0;   g4.out[0] = sF; g4.relu[0] = 1;
  g4.X[1] = catT;       g4.K[1] = 256; g4.woff[1] = 32768;  g4.boff[1] = 128; g4.out[1] = sG; g4.relu[1] = 0;
  g4.X[2] = catT;       g4.K[2] = 128; g4.woff[2] = 81920;  g4.boff[2] = 384; g4.out[2] = kT; g4.relu[2] = 0;
  g4.X[3] = catT + 128; g4.K[3] = 128; g4.woff[3] = 98304;  g4.boff[3] = 512; g4.out[3] = qT; g4.relu[3] = 0;
  mega_kern<<<dim3(2048 + 512), 512, 0, stream>>>(xyzT, posT, idx1, idx2, g4, warena, barena);

  // chain 1: v0 = mv_w2·tmp + shortb (write v0); sE = wv·v0 (vT)
  gemm_chain_kern<<<dim3(PP / 32), 256, 0, stream>>>(sF, warena, barena,
                                                     65536, 256, sG, v0,
                                                     114688, 640, sE);

  hipFuncSetAttribute((const void*)attn_mfma, hipFuncAttributeMaxDynamicSharedMemorySize, SMEM_BYTES);

  // block 1 (xyz): center=k, gathered=q, vfeat=vT; fused out: value2 = W'·agg + bias2' + vT -> sE
  attn_mfma<<<dim3(PP / 8), 512, SMEM_BYTES, stream>>>(kT, qT, xyzT, sE, idx1,
                                                       w1i1, w2i1, cw2i1, fb1,
                                                       warena + 163840, barena + 1024,
                                                       nullptr, sE, 0, flags);
  // block 2 (pos): center=q, gathered=k, vfeat=value2; fused out: y = wend·agg + bend + v0 -> d_out
  attn_mfma<<<dim3(PP / 8), 512, SMEM_BYTES, stream>>>(qT, kT, posT, sE, idx2,
                                                       w1i2, w2i2, cw2i2, fb2,
                                                       warena + 147456, barena + 896,
                                                       v0, d_out, 1, flags);
}

// Round 14
// 382.469 us; speedup vs baseline: 1.2986x; 1.2986x over previous
//
#include <hip/hip_runtime.h>
#include <hip/hip_bf16.h>

typedef __hip_bfloat16 bf16;
typedef unsigned long long ull;

#define BB 4
#define NN 2048
#define CCH 128
#define DDM 128
#define KNB 16
#define HHD 64
#define AAD 512
#define PP (BB*NN)

typedef __attribute__((ext_vector_type(8))) short short8;
typedef __attribute__((ext_vector_type(16))) float f32x16;

__device__ __forceinline__ float b2f(bf16 x) { return __bfloat162float(x); }
__device__ __forceinline__ bf16 f2b(float x) { return __float2bfloat16(x); }

__device__ __forceinline__ float ldany(const void* p, size_t i, int f32) {
  return f32 ? ((const float*)p)[i] : __bfloat162float(((const bf16*)p)[i]);
}

__device__ __forceinline__ long pack4(float a, float b, float c, float d) {
  union { bf16 h[4]; long l; } u;
  u.h[0] = f2b(a); u.h[1] = f2b(b); u.h[2] = f2b(c); u.h[3] = f2b(d);
  return u.l;
}
__device__ __forceinline__ void unpack4(long l, float* o) {
  union { bf16 h[4]; long l; } u; u.l = l;
  o[0] = b2f(u.h[0]); o[1] = b2f(u.h[1]); o[2] = b2f(u.h[2]); o[3] = b2f(u.h[3]);
}

__device__ __forceinline__ short8 ldfrag(const bf16* base, int row, int stride, int k0, int hl) {
  const bf16* p = base + (size_t)row * stride + k0 + (hl << 3);
  union { short8 v; long l[2]; } u;
  u.l[0] = *(const long*)p;
  u.l[1] = *(const long*)(p + 4);
  return u.v;
}

__device__ __forceinline__ f32x16 MFMA(short8 a, short8 b, f32x16 c) {
  return __builtin_amdgcn_mfma_f32_32x32x16_bf16(a, b, c, 0, 0, 0);
}

struct PtrArr { const void* p[36]; int n[36]; };
struct CvtTab { int src[16]; int off[16]; int n[16]; int isb[16]; };
struct G4 { const bf16* X[4]; int K[4]; int woff[4]; int boff[4]; bf16* out[4]; int relu[4]; };

// ---------- dtype sniffer ----------
__global__ __launch_bounds__(256) void sniff_kern(PtrArr pa, int* __restrict__ flags) {
  int t = blockIdx.x;
  const bf16* x = (const bf16*)pa.p[t];
  int n = pa.n[t]; if (n > 4096) n = 4096;
  __shared__ int cnt;
  if (threadIdx.x == 0) cnt = 0;
  __syncthreads();
  int c = 0;
  for (int i = threadIdx.x; i < n; i += 256) {
    float v = fabsf(__bfloat162float(x[i]));
    if (v == 0.f || (v >= 1e-6f && v <= 1024.f)) c++;
  }
  atomicAdd(&cnt, c);
  __syncthreads();
  if (threadIdx.x == 0) flags[t] = (cnt >= (n * 7) / 8) ? 0 : 1;
}

// ---------- fused convert: y<2 -> attn weight images (set=y); y>=2 -> GEMM arena entry ----------
__global__ __launch_bounds__(256) void cvtprep_kern(PtrArr pa, CvtTab tab,
                                                    const int* __restrict__ flags,
                                                    bf16* __restrict__ warena, float* __restrict__ barena,
                                                    bf16* __restrict__ w1img0, bf16* __restrict__ w2img0,
                                                    bf16* __restrict__ cw2img0, float* __restrict__ fb0,
                                                    bf16* __restrict__ w1img1, bf16* __restrict__ w2img1,
                                                    bf16* __restrict__ cw2img1, float* __restrict__ fb1) {
  int y = blockIdx.y;
  if (y >= 2) {
    int e = y - 2;
    int i = blockIdx.x * 256 + threadIdx.x;
    if (i >= tab.n[e]) return;
    float v = ldany(pa.p[tab.src[e]], i, flags[tab.src[e]]);
    if (tab.isb[e]) barena[tab.off[e] + i] = v;
    else warena[tab.off[e] + i] = f2b(v);
    return;
  }
  int set = y;
  int cIdx = set ? 20 : 16, aIdx = set ? 28 : 24, dd = set ? 2 : 3;
  bf16* w1img = set ? w1img1 : w1img0;
  bf16* w2img = set ? w2img1 : w2img0;
  bf16* cw2img = set ? cw2img1 : cw2img0;
  float* fb = set ? fb1 : fb0;
  const void* cw1 = pa.p[cIdx];     const void* cb1 = pa.p[cIdx + 1];
  const void* cw2 = pa.p[cIdx + 2]; const void* cb2 = pa.p[cIdx + 3];
  const void* aw1 = pa.p[aIdx];     const void* ab1 = pa.p[aIdx + 1];
  const void* aw2 = pa.p[aIdx + 2]; const void* ab2 = pa.p[aIdx + 3];
  int i = blockIdx.x * 256 + threadIdx.x;
  const int fcw1 = flags[cIdx], fcb1 = flags[cIdx + 1];
  const int fcw2 = flags[cIdx + 2], fcb2 = flags[cIdx + 3];
  const int faw1 = flags[aIdx], fab1 = flags[aIdx + 1];
  const int faw2 = flags[aIdx + 2], fab2 = flags[aIdx + 3];
  float* ab1f = fb;          // 512
  float* ab2f = fb + 512;    // 128
  float* cb1f = fb + 640;    // 64
  float* cb2f = fb + 704;    // 128
  float* cw1f = fb + 832;    // 192
  if (i < 65536) {                       // w1img: [h_glob 512][132]
    int hg = i >> 7, c = i & 127;
    w1img[(size_t)hg * 132 + c] = f2b(ldany(aw1, i, faw1));
  } else if (i < 131072) {               // w2img: [ac*128+o][132] col=h_local
    int j = i - 65536;
    int o = j >> 9, hh = j & 511;
    int ac = hh >> 7, hloc = hh & 127;
    w2img[(size_t)(ac * 128 + o) * 132 + hloc] = f2b(ldany(aw2, j, faw2));
  } else if (i < 139264) {               // cw2img: [o 128][68]
    int j = i - 131072;
    int o = j >> 6, h = j & 63;
    cw2img[o * 68 + h] = f2b(ldany(cw2, j, fcw2));
  } else if (i < 139776) {
    int j = i - 139264; ab1f[j] = ldany(ab1, j, fab1);
  } else if (i < 139904) {
    int j = i - 139776; ab2f[j] = ldany(ab2, j, fab2);
  } else if (i < 139968) {
    int j = i - 139904; cb1f[j] = ldany(cb1, j, fcb1);
  } else if (i < 140096) {
    int j = i - 139968; cb2f[j] = ldany(cb2, j, fcb2);
  } else if (i < 140288) {
    int j = i - 140096;
    int h = j / 3, c = j % 3;
    cw1f[j] = (c < dd) ? ldany(cw1, h * dd + c, fcw1) : 0.f;
  }
}

// ---------- fused transpose + W' prep ----------
__global__ __launch_bounds__(256) void trall_kern(const void* __restrict__ keyp,
                                                  const void* __restrict__ qryp,
                                                  const void* __restrict__ xyzp,
                                                  const void* __restrict__ posp,
                                                  const int* __restrict__ flags,
                                                  bf16* __restrict__ catT,
                                                  float* __restrict__ xyzT,
                                                  float* __restrict__ posT,
                                                  bf16* __restrict__ warena,
                                                  float* __restrict__ barena) {
  int bx = blockIdx.x;
  int tid = threadIdx.x;
  if (bx < 512) {
    __shared__ float tile[64][65];
    int xx = bx & 31, yy = (bx >> 5) & 1, zz = bx >> 6;
    int b = zz & 3, half = zz >> 2;
    const void* src = half ? qryp : keyp;
    const int f32 = flags[2 + half];
    int n0 = xx * 64, c0 = yy * 64;
    int tx = tid & 63, ty = tid >> 6;
    for (int r = ty; r < 64; r += 4)
      tile[r][tx] = ldany(src, (size_t)(b * 128 + c0 + r) * NN + n0 + tx, f32);
    __syncthreads();
    for (int r = ty; r < 64; r += 4)
      catT[(size_t)(b * NN + n0 + r) * 256 + half * 128 + c0 + tx] = __float2bfloat16(tile[tx][r]);
    return;
  }
  if (bx < 768) {
    int cb = bx - 512;
    int which = cb >> 7;
    const void* src = which ? posp : xyzp;
    float* dst = which ? posT : xyzT;
    int dd = which ? 2 : 3;
    const int f32 = flags[which];
    int i = (cb & 127) * 256 * 2 + tid;
    for (int rep = 0; rep < 2; ++rep, i += 256) {
      if (i < PP * 4) {
        int p = i >> 2, j = i & 3;
        int b = p >> 11, n = p & (NN - 1);
        dst[i] = (j < dd) ? ldany(src, (size_t)(b * dd + j) * NN + n, f32) : 0.f;
      }
    }
    return;
  }
  int bx2 = bx - 768;
  const bf16* wv = warena + 114688;
  const bf16* wkq = warena + 131072;
  if (bx2 < 64) {                       // W'[i][j] = sum_k wv[i][k]*wkq[k][j]
    int i = bx2 * 256 + tid;
    int row = i >> 7, col = i & 127;
    float acc = 0.f;
    for (int k = 0; k < 128; ++k)
      acc += b2f(wv[row * 128 + k]) * b2f(wkq[k * 128 + col]);
    warena[163840 + i] = f2b(acc);
  } else if (tid < 128) {               // bias2'[i] = sum_k wv[i][k]*bkq[k]
    float acc = 0.f;
    const float* bkq = barena + 768;
    for (int k = 0; k < 128; ++k)
      acc += b2f(wv[tid * 128 + k]) * bkq[k];
    barena[1024 + tid] = acc;
  }
}

// ---------- MEGA: bx<2048 -> kNN (both sets); bx>=2048 -> frontend gemm4 (512 thr) ----------
__global__ __launch_bounds__(512) void mega_kern(
    const float* __restrict__ xyzT, const float* __restrict__ posT,
    int* __restrict__ idx1, int* __restrict__ idx2,
    G4 g, const bf16* __restrict__ warena, const float* __restrict__ barena) {
  __shared__ __attribute__((aligned(16))) char smem[33280];
  int bx = blockIdx.x;
  int tid = threadIdx.x, lane = tid & 63, wvv = tid >> 6;
  if (bx < 2048) {
    float4* cds = (float4*)smem;
    int set = bx >> 10;
    int pblk = bx & 1023;
    const float* coordsT = set ? posT : xyzT;
    int* idxout = set ? idx2 : idx1;
    int p0 = pblk * 8, b = p0 >> 11;
    for (int j = tid; j < NN; j += 512)
      cds[j] = *(const float4*)&coordsT[((size_t)(b << 11) + j) * 4];
    __syncthreads();
    int p = p0 + wvv, n = p & (NN - 1);
    float4 cc = cds[n];
    float sqi = __fadd_rn(__fadd_rn(__fmul_rn(cc.x, cc.x), __fmul_rn(cc.y, cc.y)),
                          __fmul_rn(cc.z, cc.z));
    ull t[32];
#pragma unroll
    for (int s = 0; s < 32; ++s) {
      int j = (s << 6) | lane;
      float4 q = cds[j];
      float sqj = __fadd_rn(__fadd_rn(__fmul_rn(q.x, q.x), __fmul_rn(q.y, q.y)),
                            __fmul_rn(q.z, q.z));
      float dt  = __fadd_rn(__fadd_rn(__fmul_rn(cc.x, q.x), __fmul_rn(cc.y, q.y)),
                            __fmul_rn(cc.z, q.z));
      float d2 = __fsub_rn(__fadd_rn(sqi, sqj), __fmul_rn(2.f, dt));
      unsigned u = __float_as_uint(d2);
      u = (u & 0x80000000u) ? ~u : (u | 0x80000000u);
      t[s] = ((ull)u << 32) | (unsigned)j;
    }
    // sort each 16-half ascending (bitonic), keep lowest 16 of 32, re-sort
#pragma unroll
    for (int base = 0; base < 32; base += 16) {
#pragma unroll
      for (int k = 2; k <= 16; k <<= 1) {
#pragma unroll
        for (int j = k >> 1; j > 0; j >>= 1) {
#pragma unroll
          for (int i = 0; i < 16; ++i) {
            int l = i ^ j;
            if (l > i) {
              bool up = ((i & k) == 0);
              ull a = t[base + i], c = t[base + l];
              ull lo = a < c ? a : c;
              ull hi = a < c ? c : a;
              t[base + i] = up ? lo : hi;
              t[base + l] = up ? hi : lo;
            }
          }
        }
      }
    }
#pragma unroll
    for (int i = 0; i < 16; ++i) {      // lower half of bitonic merge-32
      ull a = t[i], c = t[31 - i];
      t[i] = a < c ? a : c;
    }
#pragma unroll
    for (int j = 8; j > 0; j >>= 1) {   // bitonic sequence -> sorted ascending
#pragma unroll
      for (int i = 0; i < 16; ++i) {
        int l = i ^ j;
        if (l > i) {
          ull a = t[i], c = t[l];
          ull lo = a < c ? a : c;
          ull hi = a < c ? c : a;
          t[i] = lo; t[l] = hi;
        }
      }
    }
    for (int r = 0; r < KNB; ++r) {
      ull h = t[0];
      ull m = h;
#pragma unroll
      for (int off = 1; off < 64; off <<= 1) {
        ull o = __shfl_xor(m, off);
        m = o < m ? o : m;
      }
      if (lane == 0) idxout[(size_t)p * KNB + r] = (int)(m & 0xffffffffu);
      if (h == m) {
#pragma unroll
        for (int i = 0; i < 15; ++i) t[i] = t[i + 1];
        t[15] = ~0ull;
      }
    }
    return;
  }
  // ---- gemm4 path ----
  {
    bf16* XT = (bf16*)smem;
    int bx2 = bx - 2048;
    int op = bx2 >> 7, ptile = bx2 & 127;
    const bf16* X = g.X[op];
    int K = g.K[op];
    const bf16* Wb = warena + g.woff[op];
    const float* bias = barena + g.boff[op];
    bf16* out = g.out[op];
    int relu = g.relu[op];
    int hl = lane >> 5, cA = lane & 31;
    int p0 = ptile * 64;
    int SK = K + 4;
    int kc = K >> 3;
    for (int c = tid; c < 64 * kc; c += 512) {
      int r = c / kc, col = (c % kc) << 3;
      *(float4*)&XT[r * SK + col] = *(const float4*)&X[(size_t)(p0 + r) * 256 + col];
    }
    __syncthreads();
    int o0 = (wvv & 3) * 32;
    int tt = wvv >> 2;
    f32x16 acc;
#pragma unroll
    for (int r = 0; r < 16; ++r) {
      int o = o0 + (r & 3) + 8 * (r >> 2) + 4 * hl;
      acc[r] = bias[o];
    }
    for (int ks = 0; ks < (K >> 4); ++ks) {
      short8 af = ldfrag(Wb, o0 + cA, K, ks * 16, hl);
      short8 b0 = ldfrag(XT, tt * 32 + cA, SK, ks * 16, hl);
      acc = MFMA(af, b0, acc);
    }
    int m = p0 + tt * 32 + cA;
#pragma unroll
    for (int q = 0; q < 4; ++q) {
      int ob = o0 + 8 * q + 4 * hl;
      float v[4] = {acc[4*q+0], acc[4*q+1], acc[4*q+2], acc[4*q+3]};
      if (relu) {
        v[0] = fmaxf(v[0], 0.f); v[1] = fmaxf(v[1], 0.f);
        v[2] = fmaxf(v[2], 0.f); v[3] = fmaxf(v[3], 0.f);
      }
      *(long*)(out + (size_t)m * 128 + ob) = pack4(v[0], v[1], v[2], v[3]);
    }
  }
}

// ---------- chained MFMA GEMM: Y1 = X·W1^T + b1 (+add1) [-> out1?]; out2 = Y1·W2^T + b2 ----------
__global__ __launch_bounds__(256) void gemm_chain_kern(
    const bf16* __restrict__ X, const bf16* __restrict__ warena,
    const float* __restrict__ barena,
    int w1off, int b1off, const bf16* __restrict__ add1, bf16* __restrict__ out1,
    int w2off, int b2off, bf16* __restrict__ out2) {
  __shared__ __attribute__((aligned(16))) bf16 XT[32 * 132];
  __shared__ __attribute__((aligned(16))) bf16 YT[32 * 132];
  int tid = threadIdx.x, lane = tid & 63, wv = tid >> 6;
  int hl = lane >> 5, cA = lane & 31;
  int p0 = blockIdx.x * 32;
  for (int c = tid; c < 32 * 16; c += 256) {
    int r = c >> 4, col = (c & 15) << 3;
    *(float4*)&XT[r * 132 + col] = *(const float4*)&X[(size_t)(p0 + r) * 128 + col];
  }
  __syncthreads();
  int o0 = wv * 32;
  const bf16* W1 = warena + w1off;
  const float* b1 = barena + b1off;
  f32x16 acc;
#pragma unroll
  for (int r = 0; r < 16; ++r) {
    int o = o0 + (r & 3) + 8 * (r >> 2) + 4 * hl;
    acc[r] = b1[o];
  }
#pragma unroll
  for (int ks = 0; ks < 8; ++ks) {
    short8 af = ldfrag(W1, o0 + cA, 128, ks * 16, hl);
    short8 b0 = ldfrag(XT, cA, 132, ks * 16, hl);
    acc = MFMA(af, b0, acc);
  }
  int m = p0 + cA;
#pragma unroll
  for (int q = 0; q < 4; ++q) {
    int ob = o0 + 8 * q + 4 * hl;
    float v[4] = {acc[4*q+0], acc[4*q+1], acc[4*q+2], acc[4*q+3]};
    if (add1) {
      float av[4];
      unpack4(*(const long*)(add1 + (size_t)m * 128 + ob), av);
      v[0] += av[0]; v[1] += av[1]; v[2] += av[2]; v[3] += av[3];
    }
    long pk = pack4(v[0], v[1], v[2], v[3]);
    *(long*)&YT[cA * 132 + ob] = pk;
    if (out1) *(long*)(out1 + (size_t)m * 128 + ob) = pk;
  }
  __syncthreads();
  const bf16* W2 = warena + w2off;
  const float* b2 = barena + b2off;
  f32x16 acc2;
#pragma unroll
  for (int r = 0; r < 16; ++r) {
    int o = o0 + (r & 3) + 8 * (r >> 2) + 4 * hl;
    acc2[r] = b2[o];
  }
#pragma unroll
  for (int ks = 0; ks < 8; ++ks) {
    short8 af = ldfrag(W2, o0 + cA, 128, ks * 16, hl);
    short8 b0 = ldfrag(YT, cA, 132, ks * 16, hl);
    acc2 = MFMA(af, b0, acc2);
  }
#pragma unroll
  for (int q = 0; q < 4; ++q) {
    int ob = o0 + 8 * q + 4 * hl;
    *(long*)(out2 + (size_t)m * 128 + ob) =
        pack4(acc2[4*q+0], acc2[4*q+1], acc2[4*q+2], acc2[4*q+3]);
  }
}

// ---------- MFMA fused kNN attention + fused output GEMM ----------
// outMode 0: out = wout·agg + bout + VF (value2) -> token-major bf16 (outAny)
// outMode 1: out = wout·agg + bout + residG    -> (B,128,N) layout (dtype flags[2])
#define SMEM_BYTES 72192
__global__ __launch_bounds__(512, 4) void attn_mfma(
    const bf16* __restrict__ centerT, const bf16* __restrict__ gatherT,
    const float* __restrict__ coordsT, const bf16* __restrict__ vfeatT,
    const int* __restrict__ idx,
    const bf16* __restrict__ w1img, const bf16* __restrict__ w2img,
    const bf16* __restrict__ cw2img, const float* __restrict__ fb,
    const bf16* __restrict__ wout, const float* __restrict__ bout,
    const bf16* __restrict__ residG, void* __restrict__ outAny, int outMode,
    const int* __restrict__ flags) {
  extern __shared__ char smem[];
  bf16* XS  = (bf16*)(smem);            // [128][132]
  bf16* HT  = (bf16*)(smem + 33792);    // [128][132]
  bf16* HC  = HT;                       // [128][68] aliases HT
  bf16* CFE = (bf16*)(smem + 67584);    // [8][128]
  bf16* VF  = (bf16*)(smem + 69632);    // [8][128]
  int*  NID = (int*)(smem + 71680);     // [128]
  const float* ab1f = fb;
  const float* ab2f = fb + 512;
  const float* cb1f = fb + 640;
  const float* cb2f = fb + 704;
  const float* cw1f = fb + 832;

  int tid = threadIdx.x, lane = tid & 63, wv = tid >> 6;
  int hl = lane >> 5, cA = lane & 31;
  int P0 = blockIdx.x * 8, b = P0 >> 11;

  if (tid < 128) NID[tid] = (b << 11) + idx[(size_t)(P0 + (tid >> 4)) * KNB + (tid & 15)];
  for (int i = tid; i < 1024; i += 512) {
    int g = i >> 7, d = i & 127;
    CFE[i] = centerT[(size_t)(P0 + g) * 128 + d];
    VF[i]  = vfeatT[(size_t)(P0 + g) * 128 + d];
  }
  __syncthreads();

  // phase 1: coord hidden HC + XS base (= cfe - gathered)
  {
    int m = tid >> 2, sub = tid & 3;
    float4 ccd = *(const float4*)&coordsT[(size_t)(P0 + (m >> 4)) * 4];
    float4 nbd = *(const float4*)&coordsT[(size_t)NID[m] * 4];
    float r0 = ccd.x - nbd.x, r1 = ccd.y - nbd.y, r2 = ccd.z - nbd.z;
    int h0 = sub * 16;
    for (int hh = h0; hh < h0 + 16; hh += 4) {
      float a0 = fmaxf(cb1f[hh+0] + cw1f[(hh+0)*3]*r0 + cw1f[(hh+0)*3+1]*r1 + cw1f[(hh+0)*3+2]*r2, 0.f);
      float a1 = fmaxf(cb1f[hh+1] + cw1f[(hh+1)*3]*r0 + cw1f[(hh+1)*3+1]*r1 + cw1f[(hh+1)*3+2]*r2, 0.f);
      float a2 = fmaxf(cb1f[hh+2] + cw1f[(hh+2)*3]*r0 + cw1f[(hh+2)*3+1]*r1 + cw1f[(hh+2)*3+2]*r2, 0.f);
      float a3 = fmaxf(cb1f[hh+3] + cw1f[(hh+3)*3]*r0 + cw1f[(hh+3)*3+1]*r1 + cw1f[(hh+3)*3+2]*r2, 0.f);
      *(long*)&HC[m * 68 + hh] = pack4(a0, a1, a2, a3);
    }
    const bf16* grow = gatherT + (size_t)NID[m] * 128 + sub * 32;
    const bf16* crow = CFE + ((m >> 4) << 7) + sub * 32;
    for (int j = 0; j < 32; j += 4) {
      float gv[4], cv[4];
      unpack4(*(const long*)(grow + j), gv);
      unpack4(*(const long*)(crow + j), cv);
      *(long*)&XS[m * 132 + sub * 32 + j] =
          pack4(cv[0] - gv[0], cv[1] - gv[1], cv[2] - gv[2], cv[3] - gv[3]);
    }
  }
  __syncthreads();

  int r0s = (wv & 3) * 32;     // output-row strip (o / h)
  int mt0 = (wv >> 2) * 64;    // token strip (2 tiles of 32)

  // preload chunk-0 W1 fragments (in flight across the emb GEMM)
  short8 pf[8];
#pragma unroll
  for (int ks = 0; ks < 8; ++ks)
    pf[ks] = ldfrag(w1img, r0s + cA, 132, ks * 16, hl);

  // phase 2: emb GEMM (C_e[o][m] = cw2 @ HC + cb2), RMW into XS
  {
    f32x16 eacc[2];
#pragma unroll
    for (int r = 0; r < 16; ++r) {
      int o = r0s + (r & 3) + 8 * (r >> 2) + 4 * hl;
      float bv = cb2f[o];
      eacc[0][r] = bv; eacc[1][r] = bv;
    }
    for (int k0 = 0; k0 < 64; k0 += 16) {
      short8 af = ldfrag(cw2img, r0s + cA, 68, k0, hl);
      short8 b0 = ldfrag(HC, mt0 + cA, 68, k0, hl);
      short8 b1 = ldfrag(HC, mt0 + 32 + cA, 68, k0, hl);
      eacc[0] = MFMA(af, b0, eacc[0]);
      eacc[1] = MFMA(af, b1, eacc[1]);
    }
#pragma unroll
    for (int t = 0; t < 2; ++t) {
      int m = mt0 + t * 32 + cA;
#pragma unroll
      for (int q = 0; q < 4; ++q) {
        int ob = r0s + 8 * q + 4 * hl;
        bf16* px = &XS[m * 132 + ob];
        float xv[4];
        unpack4(*(long*)px, xv);
        *(long*)px = pack4(xv[0] + eacc[t][4*q+0], xv[1] + eacc[t][4*q+1],
                           xv[2] + eacc[t][4*q+2], xv[3] + eacc[t][4*q+3]);
      }
    }
  }
  __syncthreads();

  // logits accumulator (bias-init)
  f32x16 acc2[2];
#pragma unroll
  for (int r = 0; r < 16; ++r) {
    int o = r0s + (r & 3) + 8 * (r >> 2) + 4 * hl;
    float bv = ab2f[o];
    acc2[0][r] = bv; acc2[1][r] = bv;
  }

  // chunk loop: 4 x 128 hidden; pf[] rotates W1(chunk ac) -> W2(ac) -> W1(ac+1)
  for (int ac = 0; ac < 4; ++ac) {
    const bf16* w2c = w2img + (size_t)ac * 16896;
    const bf16* w1n = w1img + (size_t)((ac + 1) & 3) * 16896;
    f32x16 acc1[2];
#pragma unroll
    for (int r = 0; r < 16; ++r) {
      int h = r0s + (r & 3) + 8 * (r >> 2) + 4 * hl;
      float bv = ab1f[ac * 128 + h];
      acc1[0][r] = bv; acc1[1][r] = bv;
    }
#pragma unroll
    for (int ks = 0; ks < 8; ++ks) {
      short8 af = pf[ks];
      short8 b0 = ldfrag(XS, mt0 + cA, 132, ks * 16, hl);
      short8 b1 = ldfrag(XS, mt0 + 32 + cA, 132, ks * 16, hl);
      pf[ks] = ldfrag(w2c, r0s + cA, 132, ks * 16, hl);
      acc1[0] = MFMA(af, b0, acc1[0]);
      acc1[1] = MFMA(af, b1, acc1[1]);
    }
    __syncthreads();
#pragma unroll
    for (int t = 0; t < 2; ++t) {
      int m = mt0 + t * 32 + cA;
#pragma unroll
      for (int q = 0; q < 4; ++q) {
        int hb = r0s + 8 * q + 4 * hl;
        *(long*)&HT[m * 132 + hb] =
            pack4(fmaxf(acc1[t][4*q+0], 0.f), fmaxf(acc1[t][4*q+1], 0.f),
                  fmaxf(acc1[t][4*q+2], 0.f), fmaxf(acc1[t][4*q+3], 0.f));
      }
    }
    __syncthreads();
#pragma unroll
    for (int ks = 0; ks < 8; ++ks) {
      short8 af = pf[ks];
      short8 b0 = ldfrag(HT, mt0 + cA, 132, ks * 16, hl);
      short8 b1 = ldfrag(HT, mt0 + 32 + cA, 132, ks * 16, hl);
      pf[ks] = ldfrag(w1n, r0s + cA, 132, ks * 16, hl);
      acc2[0] = MFMA(af, b0, acc2[0]);
      acc2[1] = MFMA(af, b1, acc2[1]);
    }
  }

  // stash logits into HT (bf16, [m][o] layout) -- HT dead after last GEMM2
  __syncthreads();
#pragma unroll
  for (int t = 0; t < 2; ++t) {
    int m = mt0 + t * 32 + cA;
#pragma unroll
    for (int q = 0; q < 4; ++q) {
      int ob = r0s + 8 * q + 4 * hl;
      *(long*)&HT[m * 132 + ob] = pack4(acc2[t][4*q+0], acc2[t][4*q+1],
                                        acc2[t][4*q+2], acc2[t][4*q+3]);
    }
  }
  __syncthreads();

  // shuffle-free softmax-one + aggregation: wave wv owns point g=wv; lane owns o, o+64
  float agg0, agg1v;
  {
    int g = wv;
    int base = g * 16;
    float vbase0 = b2f(VF[g * 128 + lane])      - b2f(CFE[g * 128 + lane]);
    float vbase1 = b2f(VF[g * 128 + lane + 64]) - b2f(CFE[g * 128 + lane + 64]);
#pragma unroll
    for (int half = 0; half < 2; ++half) {
      int o = lane + half * 64;
      float vb = half ? vbase1 : vbase0;
      float e[16];
      float mx = -3.4e38f;
#pragma unroll
      for (int kk = 0; kk < 16; ++kk) {
        float x = b2f(HT[(base + kk) * 132 + o]);
        e[kk] = x;
        mx = fmaxf(mx, x);
      }
      float s = 0.f;
#pragma unroll
      for (int kk = 0; kk < 16; ++kk) { e[kk] = __expf(e[kk] - mx); s += e[kk]; }
      float inv = 1.f / (1.f + s);
      float acc = 0.f;
#pragma unroll
      for (int kk = 0; kk < 16; ++kk) {
        float xv = b2f(XS[(base + kk) * 132 + o]);
        float gv = b2f(gatherT[(size_t)NID[base + kk] * 128 + o]);
        acc += (e[kk] * inv) * (vb + xv + gv);
      }
      if (half) agg1v = acc; else agg0 = acc;
    }
  }
  __syncthreads();   // all logit/XS reads done; reuse HT rows 0..7 for agg
  {
    int g = wv;
    HT[g * 132 + lane] = f2b(agg0);
    HT[g * 132 + lane + 64] = f2b(agg1v);
  }
  __syncthreads();

  // fused output GEMM: out[m][c] = wout[c]·agg[m] + bout[c] + resid[m][c]
  if (wv < 4) {
    int o0m = wv * 32;
    f32x16 acc;
#pragma unroll
    for (int r = 0; r < 16; ++r) {
      int o = o0m + (r & 3) + 8 * (r >> 2) + 4 * hl;
      acc[r] = bout[o];
    }
#pragma unroll
    for (int ks = 0; ks < 8; ++ks) {
      short8 af = ldfrag(wout, o0m + cA, 128, ks * 16, hl);
      short8 b0 = ldfrag(HT, cA, 132, ks * 16, hl);
      acc = MFMA(af, b0, acc);
    }
    int m = cA;
    if (m < 8) {
      int f32o = outMode ? flags[2] : 0;
      int gp = P0 + m;
      int gb = gp >> 11, gn = gp & (NN - 1);
#pragma unroll
      for (int q = 0; q < 4; ++q) {
        int ob = o0m + 8 * q + 4 * hl;
        float rv[4];
        if (outMode) unpack4(*(const long*)(residG + (size_t)gp * 128 + ob), rv);
        else         unpack4(*(long*)&VF[m * 128 + ob], rv);
        float v0o = acc[4*q+0] + rv[0];
        float v1o = acc[4*q+1] + rv[1];
        float v2o = acc[4*q+2] + rv[2];
        float v3o = acc[4*q+3] + rv[3];
        if (outMode) {
          float vv[4] = {v0o, v1o, v2o, v3o};
#pragma unroll
          for (int i = 0; i < 4; ++i) {
            size_t oi = (size_t)(gb * 128 + ob + i) * NN + gn;
            if (f32o) ((float*)outAny)[oi] = vv[i];
            else ((bf16*)outAny)[oi] = f2b(vv[i]);
          }
        } else {
          *(long*)((bf16*)outAny + (size_t)gp * 128 + ob) = pack4(v0o, v1o, v2o, v3o);
        }
      }
    }
  }
}

extern "C" void kernel_launch(void* const* d_in, const int* in_sizes, int n_in,
                              void* d_out, int out_size, void* d_ws, size_t ws_size,
                              hipStream_t stream) {
  // workspace layout
  int* flags = (int*)d_ws;
  bf16* catT = (bf16*)((float*)d_ws + 64);        // P x 256
  bf16* v0   = catT + (size_t)PP * 256;
  bf16* kT   = v0 + (size_t)PP * 128;
  bf16* qT   = kT + (size_t)PP * 128;
  bf16* sE   = qT + (size_t)PP * 128;             // vT, then value2 (in-place per-row)
  bf16* sF   = sE + (size_t)PP * 128;             // tmp
  bf16* sG   = sF + (size_t)PP * 128;             // shortb
  float* xyzT = (float*)(sG + (size_t)PP * 128);  // P x 4
  float* posT = xyzT + (size_t)PP * 4;
  int* idx1 = (int*)(posT + (size_t)PP * 4);      // P x 16
  int* idx2 = idx1 + (size_t)PP * KNB;            // P x 16
  bf16* w1i1 = (bf16*)(idx2 + (size_t)PP * KNB);  // 4*128*132
  bf16* w2i1 = w1i1 + 67584;
  bf16* cw2i1 = w2i1 + 67584;                     // 128*68
  bf16* w1i2 = cw2i1 + 8704;
  bf16* w2i2 = w1i2 + 67584;
  bf16* cw2i2 = w2i2 + 67584;
  float* fb1 = (float*)(cw2i2 + 8704);            // 1024 floats
  float* fb2 = fb1 + 1024;
  bf16* warena = (bf16*)(fb2 + 1024);             // 163840 + 16384 (W') bf16
  float* barena = (float*)(warena + 180224);      // 1024 + 128 fp32

  PtrArr pa;
  for (int i = 0; i < 36; ++i) { pa.p[i] = d_in[i]; pa.n[i] = in_sizes[i]; }
  sniff_kern<<<dim3(36), 256, 0, stream>>>(pa, flags);

  CvtTab tab;
  int wsrc[8] = {4, 8, 6, 10, 12, 14, 32, 34};
  int woff[8] = {0, 32768, 65536, 81920, 98304, 114688, 131072, 147456};
  int wn[8]   = {32768, 32768, 16384, 16384, 16384, 16384, 16384, 16384};
  int bsrc[8] = {5, 9, 7, 11, 13, 15, 33, 35};
  for (int e = 0; e < 8; ++e) {
    tab.src[e] = wsrc[e]; tab.off[e] = woff[e]; tab.n[e] = wn[e]; tab.isb[e] = 0;
    tab.src[8 + e] = bsrc[e]; tab.off[8 + e] = e * 128; tab.n[8 + e] = 128; tab.isb[8 + e] = 1;
  }
  cvtprep_kern<<<dim3(548, 18), 256, 0, stream>>>(pa, tab, flags, warena, barena,
                                                  w1i1, w2i1, cw2i1, fb1,
                                                  w1i2, w2i2, cw2i2, fb2);

  trall_kern<<<dim3(833), 256, 0, stream>>>(d_in[2], d_in[3], d_in[0], d_in[1],
                                            flags, catT, xyzT, posT, warena, barena);

  // MEGA: kNN (both sets) co-dispatched with the 4-op frontend GEMM
  G4 g4;
  g4.X[0] = catT;       g4.K[0] = 256; g4.woff[0] = 0;      g4.boff[0] = 0;   g4.out[0] = sF; g4.relu[0] = 1;
  g4.X[1] = catT;       g4.K[1] = 256; g4.woff[1] = 32768;  g4.boff[1] = 128; g4.out[1] = sG; g4.relu[1] = 0;
  g4.X[2] = catT;       g4.K[2] = 128; g4.woff[2] = 81920;  g4.boff[2] = 384; g4.out[2] = kT; g4.relu[2] = 0;
  g4.X[3] = catT + 128; g4.K[3] = 128; g4.woff[3] = 98304;  g4.boff[3] = 512; g4.out[3] = qT; g4.relu[3] = 0;
  mega_kern<<<dim3(2048 + 512), 512, 0, stream>>>(xyzT, posT, idx1, idx2, g4, warena, barena);

  // chain 1: v0 = mv_w2·tmp + shortb (write v0); sE = wv·v0 (vT)
  gemm_chain_kern<<<dim3(PP / 32), 256, 0, stream>>>(sF, warena, barena,
                                                     65536, 256, sG, v0,
                                                     114688, 640, sE);

  hipFuncSetAttribute((const void*)attn_mfma, hipFuncAttributeMaxDynamicSharedMemorySize, SMEM_BYTES);

  // block 1 (xyz): center=k, gathered=q, vfeat=vT; fused out: value2 = W'·agg + bias2' + vT -> sE
  attn_mfma<<<dim3(PP / 8), 512, SMEM_BYTES, stream>>>(kT, qT, xyzT, sE, idx1,
                                                       w1i1, w2i1, cw2i1, fb1,
                                                       warena + 163840, barena + 1024,
                                                       nullptr, sE, 0, flags);
  // block 2 (pos): center=q, gathered=k, vfeat=value2; fused out: y = wend·agg + bend + v0 -> d_out
  attn_mfma<<<dim3(PP / 8), 512, SMEM_BYTES, stream>>>(qT, kT, posT, sE, idx2,
                                                       w1i2, w2i2, cw2i2, fb2,
                                                       warena + 147456, barena + 896,
                                                       v0, d_out, 1, flags);
}